// Round 4
// baseline (1040.104 us; speedup 1.0000x reference)
//
#include <hip/hip_runtime.h>
#include <math.h>

// GINE GNN: 3x [fused edge-linear + gather + relu + segment-sum] + fused MLP + sigmoid head.
// R4: two-phase CSR permute (8B meta scatter + coalesced gather-permute) replaces the
//     random 64B-row scatter (R3: 204MB RMW writes, 1.87 TB/s); MLP GEMM pair fused
//     (intermediate in LDS); aggregate edge-unroll 4->8 for more outstanding gathers.

#define BLK 256

typedef __attribute__((ext_vector_type(2))) float f32x2;

__device__ inline f32x2 pk_fma(f32x2 a, f32x2 b, f32x2 c) {
    f32x2 d;
    asm("v_pk_fma_f32 %0, %1, %2, %3" : "=v"(d) : "v"(a), "v"(b), "v"(c));
    return d;
}

// ---------------- CSR build ----------------

// edge_index may be int64 (reference) or int32 (JAX x64 off). int64 LE => odd words all 0.
__global__ void detect_kernel(const unsigned int* __restrict__ ei, int* __restrict__ flag) {
    int t = blockIdx.x * blockDim.x + threadIdx.x;
    if (t < 1024) {
        if (ei[2 * t + 1] != 0u) atomicOr(flag, 1);  // nonzero odd word => int32 mode
    }
}

// convert + histogram fused
__global__ void convert_hist_kernel(const int* __restrict__ ei32, const long long* __restrict__ ei64,
                                    const int* __restrict__ flag, int E,
                                    int* __restrict__ src, int* __restrict__ dst,
                                    int* __restrict__ counts) {
    int e = blockIdx.x * blockDim.x + threadIdx.x;
    if (e >= E) return;
    int s, d;
    if (*flag) { s = ei32[e]; d = ei32[E + e]; }
    else       { s = (int)ei64[e]; d = (int)ei64[E + e]; }
    src[e] = s; dst[e] = d;
    atomicAdd(&counts[d], 1);
}

// single-block scan: 256 threads, each owns a contiguous chunk
__global__ void scan_kernel(const int* __restrict__ counts, int* __restrict__ offsets, int n) {
    __shared__ int tsum[256];
    __shared__ int texcl[256];
    int t = threadIdx.x;
    int chunk = (n + 255) >> 8;
    int b = t * chunk, e = min(b + chunk, n);
    int s = 0;
    for (int i = b; i < e; i++) s += counts[i];
    tsum[t] = s;
    __syncthreads();
    if (t == 0) {
        int run = 0;
        for (int i = 0; i < 256; i++) { texcl[i] = run; run += tsum[i]; }
        offsets[n] = run;  // == E
    }
    __syncthreads();
    int run = texcl[t];
    for (int i = b; i < e; i++) { offsets[i] = run; run += counts[i]; }
}

// phase 1: scatter only the 8B {src, eid} record (12.8MB target, L2-friendly)
__global__ void scatter_pos_kernel(const int* __restrict__ src, const int* __restrict__ dst,
                                   const int* __restrict__ offsets, int* __restrict__ cursor,
                                   int2* __restrict__ meta, int E) {
    int e = blockIdx.x * blockDim.x + threadIdx.x;
    if (e >= E) return;
    int d = dst[e];
    int pos = offsets[d] + atomicAdd(&cursor[d], 1);
    meta[pos] = make_int2(src[e], e);
}

// phase 2: coalesced-write permute; 4 threads per edge (one float4 chunk each)
__global__ void permute_gather_kernel(const int2* __restrict__ meta,
                                      const float4* __restrict__ ea4,
                                      int* __restrict__ srcp, float4* __restrict__ eap4, int E) {
    int t = blockIdx.x * blockDim.x + threadIdx.x;
    if (t >= E * 4) return;
    int pos = t >> 2, c = t & 3;
    int2 m = meta[pos];
    eap4[(size_t)pos * 4 + c] = ea4[(size_t)m.y * 4 + c];
    if (c == 0) srcp[pos] = m.x;
}

// ---------------- fused aggregation ----------------
// h[node] = x[node] + sum_{e: dst=node} relu( x[src_e] + ea_e @ We + be )
// One wave per node; lane owns C=D/64 channels; edge-linear via v_pk_fma_f32;
// edge loop unrolled x8 (8 outstanding gather chains).
template <int D>
__global__ __launch_bounds__(256) void aggregate_kernel(
    const float* __restrict__ x, const float* __restrict__ eap,
    const int* __restrict__ srcp,
    const float* __restrict__ We, const float* __restrict__ be,
    const int* __restrict__ offsets,
    float* __restrict__ h, int n) {
    constexpr int C = D / 64;
    int lane = threadIdx.x & 63;
    int node = __builtin_amdgcn_readfirstlane(blockIdx.x * 4 + (threadIdx.x >> 6));
    if (node >= n) return;
    int c0 = lane * C;

    // weights packed over k-pairs: wp[j][t] = {We[2t][c0+j], We[2t+1][c0+j]}
    f32x2 wp[C][8];
#pragma unroll
    for (int j = 0; j < C; j++)
#pragma unroll
        for (int t = 0; t < 8; t++) {
            f32x2 v; v.x = We[(2 * t) * D + c0 + j]; v.y = We[(2 * t + 1) * D + c0 + j];
            wp[j][t] = v;
        }
    float bias[C], acc[C];
#pragma unroll
    for (int j = 0; j < C; j++) {
        bias[j] = be[c0 + j];
        acc[j] = x[(size_t)node * D + c0 + j];
    }
    int p = offsets[node], pe = offsets[node + 1];

    // main loop: 8 edges per iteration, all 8 x-gathers issued before compute
    for (; p + 8 <= pe; p += 8) {
        int s[8];
#pragma unroll
        for (int u = 0; u < 8; u++) s[u] = srcp[p + u];
        float xv[8][C];
#pragma unroll
        for (int u = 0; u < 8; u++) {
            const float* r = x + (size_t)s[u] * D + c0;
            if constexpr (C == 2) { float2 tv = *(const float2*)r; xv[u][0] = tv.x; xv[u][1] = tv.y; }
            else xv[u][0] = *r;
        }
#pragma unroll
        for (int u = 0; u < 8; u++) {
            const float4* er = (const float4*)(eap + (size_t)(p + u) * 16);
            float4 e0 = er[0], e1 = er[1], e2 = er[2], e3 = er[3];
            f32x2 ev[8];
            ev[0].x = e0.x; ev[0].y = e0.y;  ev[1].x = e0.z; ev[1].y = e0.w;
            ev[2].x = e1.x; ev[2].y = e1.y;  ev[3].x = e1.z; ev[3].y = e1.w;
            ev[4].x = e2.x; ev[4].y = e2.y;  ev[5].x = e2.z; ev[5].y = e2.w;
            ev[6].x = e3.x; ev[6].y = e3.y;  ev[7].x = e3.z; ev[7].y = e3.w;
#pragma unroll
            for (int j = 0; j < C; j++) {
                f32x2 prod; prod.x = xv[u][j] + bias[j]; prod.y = 0.f;
#pragma unroll
                for (int t = 0; t < 8; t++) prod = pk_fma(ev[t], wp[j][t], prod);
                acc[j] += fmaxf(prod.x + prod.y, 0.f);
            }
        }
    }
    // tail (<= 7 edges)
    for (; p < pe; p++) {
        int s = srcp[p];
        const float* xr = x + (size_t)s * D + c0;
        float xv[C];
        if constexpr (C == 2) { float2 t = *(const float2*)xr; xv[0] = t.x; xv[1] = t.y; }
        else xv[0] = *xr;
        const float4* er = (const float4*)(eap + (size_t)p * 16);
        float4 e0 = er[0], e1 = er[1], e2 = er[2], e3 = er[3];
        f32x2 ev[8];
        ev[0].x = e0.x; ev[0].y = e0.y;  ev[1].x = e0.z; ev[1].y = e0.w;
        ev[2].x = e1.x; ev[2].y = e1.y;  ev[3].x = e1.z; ev[3].y = e1.w;
        ev[4].x = e2.x; ev[4].y = e2.y;  ev[5].x = e2.z; ev[5].y = e2.w;
        ev[6].x = e3.x; ev[6].y = e3.y;  ev[7].x = e3.z; ev[7].y = e3.w;
#pragma unroll
        for (int j = 0; j < C; j++) {
            f32x2 prod; prod.x = xv[j] + bias[j]; prod.y = 0.f;
#pragma unroll
            for (int t = 0; t < 8; t++) prod = pk_fma(ev[t], wp[j][t], prod);
            acc[j] += fmaxf(prod.x + prod.y, 0.f);
        }
    }
#pragma unroll
    for (int j = 0; j < C; j++) h[(size_t)node * D + c0 + j] = acc[j];
}

// ---------------- fused MLP: C[n,128] = relu( relu(A[n,K]@W1+b1) @ W2 + b2 ) ----------------
// 64-row tile per block; the 64x128 intermediate lives in LDS (no bufB round-trip).
template <int K>
__global__ __launch_bounds__(256) void mlp_kernel(
    const float* __restrict__ A, const float* __restrict__ W1, const float* __restrict__ b1,
    const float* __restrict__ W2, const float* __restrict__ b2,
    float* __restrict__ C, int n) {
    __shared__ __align__(16) float As[16][68];    // transposed A tile, padded
    __shared__ __align__(16) float Bs[16][128];   // weight chunk
    __shared__ __align__(16) float Ts[64][132];   // stage-1 result, padded
    int t = threadIdx.x;
    int row0 = blockIdx.x * 64;
    int tr = t >> 5, tc = t & 31;  // rows tr*8..+8, cols tc*4..+4
    float acc[8][4];
#pragma unroll
    for (int r = 0; r < 8; r++)
#pragma unroll
        for (int c = 0; c < 4; c++) acc[r][c] = 0.f;

    int lr = t >> 2, lk = (t & 3) * 4;   // A staging: row lr, k-offset lk
    int bk = t >> 4, bc = (t & 15) * 8;  // B staging

    // ---- stage 1: Ts = relu(A @ W1 + b1) ----
    for (int ks = 0; ks < K; ks += 16) {
        float4 a;
        int grow = row0 + lr;
        if (grow < n) a = *(const float4*)(A + (size_t)grow * K + ks + lk);
        else a = make_float4(0.f, 0.f, 0.f, 0.f);
        As[lk + 0][lr] = a.x; As[lk + 1][lr] = a.y;
        As[lk + 2][lr] = a.z; As[lk + 3][lr] = a.w;

        const float4* bp = (const float4*)(W1 + (size_t)(ks + bk) * 128 + bc);
        float4 b0 = bp[0], b1v = bp[1];
        *(float4*)&Bs[bk][bc] = b0;
        *(float4*)&Bs[bk][bc + 4] = b1v;
        __syncthreads();
#pragma unroll
        for (int kk = 0; kk < 16; kk++) {
            float4 a0 = *(const float4*)&As[kk][tr * 8];
            float4 a1 = *(const float4*)&As[kk][tr * 8 + 4];
            float4 bv = *(const float4*)&Bs[kk][tc * 4];
            float ar[8] = {a0.x, a0.y, a0.z, a0.w, a1.x, a1.y, a1.z, a1.w};
            float bc4[4] = {bv.x, bv.y, bv.z, bv.w};
#pragma unroll
            for (int r = 0; r < 8; r++)
#pragma unroll
                for (int c = 0; c < 4; c++) acc[r][c] = fmaf(ar[r], bc4[c], acc[r][c]);
        }
        __syncthreads();
    }
    {
        float4 bb = *(const float4*)(b1 + tc * 4);
#pragma unroll
        for (int r = 0; r < 8; r++) {
            Ts[tr * 8 + r][tc * 4 + 0] = fmaxf(acc[r][0] + bb.x, 0.f);
            Ts[tr * 8 + r][tc * 4 + 1] = fmaxf(acc[r][1] + bb.y, 0.f);
            Ts[tr * 8 + r][tc * 4 + 2] = fmaxf(acc[r][2] + bb.z, 0.f);
            Ts[tr * 8 + r][tc * 4 + 3] = fmaxf(acc[r][3] + bb.w, 0.f);
        }
    }
    __syncthreads();

    // ---- stage 2: C = relu(Ts @ W2 + b2) ----
#pragma unroll
    for (int r = 0; r < 8; r++)
#pragma unroll
        for (int c = 0; c < 4; c++) acc[r][c] = 0.f;
    for (int ks = 0; ks < 128; ks += 16) {
        const float4* bp = (const float4*)(W2 + (size_t)(ks + bk) * 128 + bc);
        float4 b0 = bp[0], b1v = bp[1];
        *(float4*)&Bs[bk][bc] = b0;
        *(float4*)&Bs[bk][bc + 4] = b1v;
        __syncthreads();
#pragma unroll
        for (int kk = 0; kk < 16; kk++) {
            float4 bv = *(const float4*)&Bs[kk][tc * 4];
            float bc4[4] = {bv.x, bv.y, bv.z, bv.w};
            float ar[8];
#pragma unroll
            for (int r = 0; r < 8; r++) ar[r] = Ts[tr * 8 + r][ks + kk];
#pragma unroll
            for (int r = 0; r < 8; r++)
#pragma unroll
                for (int c = 0; c < 4; c++) acc[r][c] = fmaf(ar[r], bc4[c], acc[r][c]);
        }
        __syncthreads();
    }
    float4 bb = *(const float4*)(b2 + tc * 4);
#pragma unroll
    for (int r = 0; r < 8; r++) {
        int grow = row0 + tr * 8 + r;
        if (grow < n) {
            float4 v;
            v.x = fmaxf(acc[r][0] + bb.x, 0.f);
            v.y = fmaxf(acc[r][1] + bb.y, 0.f);
            v.z = fmaxf(acc[r][2] + bb.z, 0.f);
            v.w = fmaxf(acc[r][3] + bb.w, 0.f);
            *(float4*)(C + (size_t)grow * 128 + tc * 4) = v;
        }
    }
}

// ---------------- head: out = sigmoid(x @ Wlin + blin) ----------------
__global__ __launch_bounds__(256) void final_kernel(
    const float* __restrict__ x, const float* __restrict__ Wlin,
    const float* __restrict__ blin, float* __restrict__ out, int n) {
    int lane = threadIdx.x & 63;
    int node = blockIdx.x * 4 + (threadIdx.x >> 6);
    if (node >= n) return;
    float2 w = *(const float2*)(Wlin + lane * 2);
    float2 xv = *(const float2*)(x + (size_t)node * 128 + lane * 2);
    float v = xv.x * w.x + xv.y * w.y;
#pragma unroll
    for (int off = 32; off; off >>= 1) v += __shfl_down(v, off, 64);
    if (lane == 0) out[node] = 1.f / (1.f + expf(-(v + blin[0])));
}

// ---------------- launch ----------------
extern "C" void kernel_launch(void* const* d_in, const int* in_sizes, int n_in,
                              void* d_out, int out_size, void* d_ws, size_t ws_size,
                              hipStream_t stream) {
    const float* x_in = (const float*)d_in[0];
    const void* ei    = d_in[1];
    const float* ea   = (const float*)d_in[2];
    const float* We[3]  = {(const float*)d_in[3], (const float*)d_in[9],  (const float*)d_in[15]};
    const float* be[3]  = {(const float*)d_in[4], (const float*)d_in[10], (const float*)d_in[16]};
    const float* W1[3]  = {(const float*)d_in[5], (const float*)d_in[11], (const float*)d_in[17]};
    const float* b1[3]  = {(const float*)d_in[6], (const float*)d_in[12], (const float*)d_in[18]};
    const float* W2[3]  = {(const float*)d_in[7], (const float*)d_in[13], (const float*)d_in[19]};
    const float* b2[3]  = {(const float*)d_in[8], (const float*)d_in[14], (const float*)d_in[20]};
    const float* Wlin = (const float*)d_in[21];
    const float* blin = (const float*)d_in[22];
    float* out = (float*)d_out;

    const int N = in_sizes[0] / 64;   // 50000
    const int E = in_sizes[1] / 2;    // 1.6M

    size_t off = 0;
    auto alloc = [&](size_t bytes) {
        void* p = (char*)d_ws + off;
        off += (bytes + 255) & ~(size_t)255;
        return p;
    };
    int*   flag    = (int*)alloc(4);
    int*   src32   = (int*)alloc((size_t)E * 4);
    int*   dst32   = (int*)alloc((size_t)E * 4);
    int*   counts  = (int*)alloc((size_t)N * 4);
    int*   offsets = (int*)alloc((size_t)(N + 1) * 4);
    int*   cursor  = (int*)alloc((size_t)N * 4);
    int2*  meta    = (int2*)alloc((size_t)E * 8);
    int*   srcp    = (int*)alloc((size_t)E * 4);
    float* eap     = (float*)alloc((size_t)E * 16 * 4);
    float* bufA    = (float*)alloc((size_t)N * 128 * 4);
    float* bufC    = (float*)alloc((size_t)N * 128 * 4);

    hipMemsetAsync(flag, 0, 4, stream);
    hipMemsetAsync(counts, 0, (size_t)N * 4, stream);
    hipMemsetAsync(cursor, 0, (size_t)N * 4, stream);

    int egrid = (E + BLK - 1) / BLK;
    detect_kernel<<<4, BLK, 0, stream>>>((const unsigned int*)ei, flag);
    convert_hist_kernel<<<egrid, BLK, 0, stream>>>((const int*)ei, (const long long*)ei, flag, E,
                                                   src32, dst32, counts);
    scan_kernel<<<1, BLK, 0, stream>>>(counts, offsets, N);
    scatter_pos_kernel<<<egrid, BLK, 0, stream>>>(src32, dst32, offsets, cursor, meta, E);
    permute_gather_kernel<<<(E * 4 + BLK - 1) / BLK, BLK, 0, stream>>>(
        meta, (const float4*)ea, srcp, (float4*)eap, E);

    int ngrid4 = (N + 3) / 4;
    int ggrid  = (N + 63) / 64;

    // layer 0: d=64
    aggregate_kernel<64><<<ngrid4, BLK, 0, stream>>>(x_in, eap, srcp, We[0], be[0], offsets, bufA, N);
    mlp_kernel<64><<<ggrid, BLK, 0, stream>>>(bufA, W1[0], b1[0], W2[0], b2[0], bufC, N);
    // layer 1: d=128
    aggregate_kernel<128><<<ngrid4, BLK, 0, stream>>>(bufC, eap, srcp, We[1], be[1], offsets, bufA, N);
    mlp_kernel<128><<<ggrid, BLK, 0, stream>>>(bufA, W1[1], b1[1], W2[1], b2[1], bufC, N);
    // layer 2: d=128
    aggregate_kernel<128><<<ngrid4, BLK, 0, stream>>>(bufC, eap, srcp, We[2], be[2], offsets, bufA, N);
    mlp_kernel<128><<<ggrid, BLK, 0, stream>>>(bufA, W1[2], b1[2], W2[2], b2[2], bufC, N);

    final_kernel<<<ngrid4, BLK, 0, stream>>>(bufC, Wlin, blin, out, N);
}

// Round 6
// 996.349 us; speedup vs baseline: 1.0439x; 1.0439x over previous
//
#include <hip/hip_runtime.h>
#include <math.h>

// GINE GNN: 3x [fused edge-linear + gather + relu + segment-sum] + fused MLP (+head) on MI355X.
// R6 (= R5 with compile fix): union-based f32x2 extraction replaces __builtin_shufflevector
//     (which requires literal-constant indices). Aggregate unroll x4; v_pk_fma_f32 takes the
//     wave-uniform edge operand from SGPRs ("s" constraint); CSR build reads edge_index
//     directly; sigmoid head fused into layer-2 MLP epilogue.

#define BLK 256

typedef __attribute__((ext_vector_type(2))) float f32x2;
typedef __attribute__((ext_vector_type(16))) float f32x16;

// v_pk_fma_f32 with wave-uniform src0 in SGPR pair (VOP3P: max 1 sgpr operand - ok)
__device__ inline f32x2 pk_fma_s(f32x2 a_uniform, f32x2 b, f32x2 c) {
    f32x2 d;
    asm("v_pk_fma_f32 %0, %1, %2, %3" : "=v"(d) : "s"(a_uniform), "v"(b), "v"(c));
    return d;
}

union EdgeRow {
    f32x16 v;
    f32x2 p[8];
};

// ---------------- CSR build ----------------

// edge_index may be int64 (reference) or int32 (JAX x64 off). int64 LE => odd words all 0.
__global__ void detect_kernel(const unsigned int* __restrict__ ei, int* __restrict__ flag) {
    int t = blockIdx.x * blockDim.x + threadIdx.x;
    if (t < 1024) {
        if (ei[2 * t + 1] != 0u) atomicOr(flag, 1);  // nonzero odd word => int32 mode
    }
}

__global__ void hist_kernel(const void* __restrict__ ei, const int* __restrict__ flag, int E,
                            int* __restrict__ counts) {
    int e = blockIdx.x * blockDim.x + threadIdx.x;
    if (e >= E) return;
    int d = (*flag) ? ((const int*)ei)[E + e] : (int)((const long long*)ei)[E + e];
    atomicAdd(&counts[d], 1);
}

// single-block scan: 256 threads, each owns a contiguous chunk
__global__ void scan_kernel(const int* __restrict__ counts, int* __restrict__ offsets, int n) {
    __shared__ int tsum[256];
    __shared__ int texcl[256];
    int t = threadIdx.x;
    int chunk = (n + 255) >> 8;
    int b = t * chunk, e = min(b + chunk, n);
    int s = 0;
    for (int i = b; i < e; i++) s += counts[i];
    tsum[t] = s;
    __syncthreads();
    if (t == 0) {
        int run = 0;
        for (int i = 0; i < 256; i++) { texcl[i] = run; run += tsum[i]; }
        offsets[n] = run;  // == E
    }
    __syncthreads();
    int run = texcl[t];
    for (int i = b; i < e; i++) { offsets[i] = run; run += counts[i]; }
}

// phase 1: scatter only the 8B {src, eid} record (12.8MB target, L2-friendly)
__global__ void scatter_pos_kernel(const void* __restrict__ ei, const int* __restrict__ flag,
                                   const int* __restrict__ offsets, int* __restrict__ cursor,
                                   int2* __restrict__ meta, int E) {
    int e = blockIdx.x * blockDim.x + threadIdx.x;
    if (e >= E) return;
    int s, d;
    if (*flag) { s = ((const int*)ei)[e]; d = ((const int*)ei)[E + e]; }
    else       { s = (int)((const long long*)ei)[e]; d = (int)((const long long*)ei)[E + e]; }
    int pos = offsets[d] + atomicAdd(&cursor[d], 1);
    meta[pos] = make_int2(s, e);
}

// phase 2: coalesced-write permute; 4 threads per edge (one float4 chunk each)
__global__ void permute_gather_kernel(const int2* __restrict__ meta,
                                      const float4* __restrict__ ea4,
                                      int* __restrict__ srcp, float4* __restrict__ eap4, int E) {
    int t = blockIdx.x * blockDim.x + threadIdx.x;
    if (t >= E * 4) return;
    int pos = t >> 2, c = t & 3;
    int2 m = meta[pos];
    eap4[(size_t)pos * 4 + c] = ea4[(size_t)m.y * 4 + c];
    if (c == 0) srcp[pos] = m.x;
}

// ---------------- fused aggregation ----------------
// h[node] = x[node] + sum_{e: dst=node} relu( x[src_e] + ea_e @ We + be )
// One wave per node; lane owns C=D/64 channels. Edge attrs are wave-uniform: loaded via
// scalar cache (f32x16 -> s_load_dwordx16) and fed to v_pk_fma_f32 as the SGPR operand.
template <int D>
__global__ __launch_bounds__(256) void aggregate_kernel(
    const float* __restrict__ x, const float* __restrict__ eap,
    const int* __restrict__ srcp,
    const float* __restrict__ We, const float* __restrict__ be,
    const int* __restrict__ offsets,
    float* __restrict__ h, int n) {
    constexpr int C = D / 64;
    int lane = threadIdx.x & 63;
    int node = __builtin_amdgcn_readfirstlane(blockIdx.x * 4 + (threadIdx.x >> 6));
    if (node >= n) return;
    int c0 = lane * C;

    // weights packed over k-pairs: wp[j][t] = {We[2t][c0+j], We[2t+1][c0+j]}  (VGPR, lane-varying)
    f32x2 wp[C][8];
#pragma unroll
    for (int j = 0; j < C; j++)
#pragma unroll
        for (int t = 0; t < 8; t++) {
            f32x2 v; v.x = We[(2 * t) * D + c0 + j]; v.y = We[(2 * t + 1) * D + c0 + j];
            wp[j][t] = v;
        }
    float bias[C], acc[C];
#pragma unroll
    for (int j = 0; j < C; j++) {
        bias[j] = be[c0 + j];
        acc[j] = x[(size_t)node * D + c0 + j];
    }
    int p = offsets[node], pe = offsets[node + 1];

    // main loop: 4 edges per iteration, x-gathers issued up front
    for (; p + 4 <= pe; p += 4) {
        int s0 = srcp[p], s1 = srcp[p + 1], s2 = srcp[p + 2], s3 = srcp[p + 3];
        float xv[4][C];
        {
            const float* r0 = x + (size_t)s0 * D + c0;
            const float* r1 = x + (size_t)s1 * D + c0;
            const float* r2 = x + (size_t)s2 * D + c0;
            const float* r3 = x + (size_t)s3 * D + c0;
            if constexpr (C == 2) {
                float2 t0 = *(const float2*)r0, t1 = *(const float2*)r1;
                float2 t2 = *(const float2*)r2, t3 = *(const float2*)r3;
                xv[0][0] = t0.x; xv[0][1] = t0.y; xv[1][0] = t1.x; xv[1][1] = t1.y;
                xv[2][0] = t2.x; xv[2][1] = t2.y; xv[3][0] = t3.x; xv[3][1] = t3.y;
            } else {
                xv[0][0] = *r0; xv[1][0] = *r1; xv[2][0] = *r2; xv[3][0] = *r3;
            }
        }
#pragma unroll
        for (int u = 0; u < 4; u++) {
            EdgeRow er;
            er.v = *(const f32x16*)(eap + (size_t)(p + u) * 16);  // wave-uniform -> SMEM
#pragma unroll
            for (int j = 0; j < C; j++) {
                f32x2 prod; prod.x = xv[u][j] + bias[j]; prod.y = 0.f;
#pragma unroll
                for (int t = 0; t < 8; t++) prod = pk_fma_s(er.p[t], wp[j][t], prod);
                acc[j] += fmaxf(prod.x + prod.y, 0.f);
            }
        }
    }
    // tail (<= 3 edges)
    for (; p < pe; p++) {
        int s = srcp[p];
        const float* xr = x + (size_t)s * D + c0;
        float xv[C];
        if constexpr (C == 2) { float2 t = *(const float2*)xr; xv[0] = t.x; xv[1] = t.y; }
        else xv[0] = *xr;
        EdgeRow er;
        er.v = *(const f32x16*)(eap + (size_t)p * 16);
#pragma unroll
        for (int j = 0; j < C; j++) {
            f32x2 prod; prod.x = xv[j] + bias[j]; prod.y = 0.f;
#pragma unroll
            for (int t = 0; t < 8; t++) prod = pk_fma_s(er.p[t], wp[j][t], prod);
            acc[j] += fmaxf(prod.x + prod.y, 0.f);
        }
    }
#pragma unroll
    for (int j = 0; j < C; j++) h[(size_t)node * D + c0 + j] = acc[j];
}

// ---------------- fused MLP: relu( relu(A@W1+b1) @ W2 + b2 ), optional sigmoid head ----------
// 64-row tile per block; 64x128 intermediate in LDS. HEAD: out[row]=sigmoid(res@Wlin+blin),
// C store skipped (layer-2 output only feeds the head).
template <int K, bool HEAD>
__global__ __launch_bounds__(256) void mlp_kernel(
    const float* __restrict__ A, const float* __restrict__ W1, const float* __restrict__ b1,
    const float* __restrict__ W2, const float* __restrict__ b2,
    float* __restrict__ C, const float* __restrict__ Wlin, const float* __restrict__ blin,
    float* __restrict__ out, int n) {
    __shared__ __align__(16) float As[16][68];    // transposed A tile, padded
    __shared__ __align__(16) float Bs[16][128];   // weight chunk
    __shared__ __align__(16) float Ts[64][132];   // stage-1 result, padded
    int t = threadIdx.x;
    int row0 = blockIdx.x * 64;
    int tr = t >> 5, tc = t & 31;  // rows tr*8..+8, cols tc*4..+4
    float acc[8][4];
#pragma unroll
    for (int r = 0; r < 8; r++)
#pragma unroll
        for (int c = 0; c < 4; c++) acc[r][c] = 0.f;

    int lr = t >> 2, lk = (t & 3) * 4;   // A staging: row lr, k-offset lk
    int bk = t >> 4, bc = (t & 15) * 8;  // B staging

    // ---- stage 1: Ts = relu(A @ W1 + b1) ----
    for (int ks = 0; ks < K; ks += 16) {
        float4 a;
        int grow = row0 + lr;
        if (grow < n) a = *(const float4*)(A + (size_t)grow * K + ks + lk);
        else a = make_float4(0.f, 0.f, 0.f, 0.f);
        As[lk + 0][lr] = a.x; As[lk + 1][lr] = a.y;
        As[lk + 2][lr] = a.z; As[lk + 3][lr] = a.w;

        const float4* bp = (const float4*)(W1 + (size_t)(ks + bk) * 128 + bc);
        float4 b0 = bp[0], b1v = bp[1];
        *(float4*)&Bs[bk][bc] = b0;
        *(float4*)&Bs[bk][bc + 4] = b1v;
        __syncthreads();
#pragma unroll
        for (int kk = 0; kk < 16; kk++) {
            float4 a0 = *(const float4*)&As[kk][tr * 8];
            float4 a1 = *(const float4*)&As[kk][tr * 8 + 4];
            float4 bv = *(const float4*)&Bs[kk][tc * 4];
            float ar[8] = {a0.x, a0.y, a0.z, a0.w, a1.x, a1.y, a1.z, a1.w};
            float bc4[4] = {bv.x, bv.y, bv.z, bv.w};
#pragma unroll
            for (int r = 0; r < 8; r++)
#pragma unroll
                for (int c = 0; c < 4; c++) acc[r][c] = fmaf(ar[r], bc4[c], acc[r][c]);
        }
        __syncthreads();
    }
    {
        float4 bb = *(const float4*)(b1 + tc * 4);
#pragma unroll
        for (int r = 0; r < 8; r++) {
            Ts[tr * 8 + r][tc * 4 + 0] = fmaxf(acc[r][0] + bb.x, 0.f);
            Ts[tr * 8 + r][tc * 4 + 1] = fmaxf(acc[r][1] + bb.y, 0.f);
            Ts[tr * 8 + r][tc * 4 + 2] = fmaxf(acc[r][2] + bb.z, 0.f);
            Ts[tr * 8 + r][tc * 4 + 3] = fmaxf(acc[r][3] + bb.w, 0.f);
        }
    }
    __syncthreads();

    // ---- stage 2: res = relu(Ts @ W2 + b2) ----
#pragma unroll
    for (int r = 0; r < 8; r++)
#pragma unroll
        for (int c = 0; c < 4; c++) acc[r][c] = 0.f;
    for (int ks = 0; ks < 128; ks += 16) {
        const float4* bp = (const float4*)(W2 + (size_t)(ks + bk) * 128 + bc);
        float4 b0 = bp[0], b1v = bp[1];
        *(float4*)&Bs[bk][bc] = b0;
        *(float4*)&Bs[bk][bc + 4] = b1v;
        __syncthreads();
#pragma unroll
        for (int kk = 0; kk < 16; kk++) {
            float4 bv = *(const float4*)&Bs[kk][tc * 4];
            float bc4[4] = {bv.x, bv.y, bv.z, bv.w};
            float ar[8];
#pragma unroll
            for (int r = 0; r < 8; r++) ar[r] = Ts[tr * 8 + r][ks + kk];
#pragma unroll
            for (int r = 0; r < 8; r++)
#pragma unroll
                for (int c = 0; c < 4; c++) acc[r][c] = fmaf(ar[r], bc4[c], acc[r][c]);
        }
        __syncthreads();
    }
    float4 bb = *(const float4*)(b2 + tc * 4);
    if constexpr (HEAD) {
        float4 wl = *(const float4*)(Wlin + tc * 4);
        float bl = *blin;
#pragma unroll
        for (int r = 0; r < 8; r++) {
            float v0 = fmaxf(acc[r][0] + bb.x, 0.f);
            float v1 = fmaxf(acc[r][1] + bb.y, 0.f);
            float v2 = fmaxf(acc[r][2] + bb.z, 0.f);
            float v3 = fmaxf(acc[r][3] + bb.w, 0.f);
            float part = v0 * wl.x + v1 * wl.y + v2 * wl.z + v3 * wl.w;
#pragma unroll
            for (int m = 1; m <= 16; m <<= 1) part += __shfl_xor(part, m, 64);
            int grow = row0 + tr * 8 + r;
            if (tc == 0 && grow < n) out[grow] = 1.f / (1.f + expf(-(part + bl)));
        }
    } else {
#pragma unroll
        for (int r = 0; r < 8; r++) {
            int grow = row0 + tr * 8 + r;
            if (grow < n) {
                float4 v;
                v.x = fmaxf(acc[r][0] + bb.x, 0.f);
                v.y = fmaxf(acc[r][1] + bb.y, 0.f);
                v.z = fmaxf(acc[r][2] + bb.z, 0.f);
                v.w = fmaxf(acc[r][3] + bb.w, 0.f);
                *(float4*)(C + (size_t)grow * 128 + tc * 4) = v;
            }
        }
    }
}

// ---------------- launch ----------------
extern "C" void kernel_launch(void* const* d_in, const int* in_sizes, int n_in,
                              void* d_out, int out_size, void* d_ws, size_t ws_size,
                              hipStream_t stream) {
    const float* x_in = (const float*)d_in[0];
    const void* ei    = d_in[1];
    const float* ea   = (const float*)d_in[2];
    const float* We[3]  = {(const float*)d_in[3], (const float*)d_in[9],  (const float*)d_in[15]};
    const float* be[3]  = {(const float*)d_in[4], (const float*)d_in[10], (const float*)d_in[16]};
    const float* W1[3]  = {(const float*)d_in[5], (const float*)d_in[11], (const float*)d_in[17]};
    const float* b1[3]  = {(const float*)d_in[6], (const float*)d_in[12], (const float*)d_in[18]};
    const float* W2[3]  = {(const float*)d_in[7], (const float*)d_in[13], (const float*)d_in[19]};
    const float* b2[3]  = {(const float*)d_in[8], (const float*)d_in[14], (const float*)d_in[20]};
    const float* Wlin = (const float*)d_in[21];
    const float* blin = (const float*)d_in[22];
    float* out = (float*)d_out;

    const int N = in_sizes[0] / 64;   // 50000
    const int E = in_sizes[1] / 2;    // 1.6M

    size_t off = 0;
    auto alloc = [&](size_t bytes) {
        void* p = (char*)d_ws + off;
        off += (bytes + 255) & ~(size_t)255;
        return p;
    };
    int*   flag    = (int*)alloc(4);
    int*   counts  = (int*)alloc((size_t)N * 4);
    int*   offsets = (int*)alloc((size_t)(N + 1) * 4);
    int*   cursor  = (int*)alloc((size_t)N * 4);
    int2*  meta    = (int2*)alloc((size_t)E * 8);
    int*   srcp    = (int*)alloc((size_t)E * 4);
    float* eap     = (float*)alloc((size_t)E * 16 * 4);
    float* bufA    = (float*)alloc((size_t)N * 128 * 4);
    float* bufC    = (float*)alloc((size_t)N * 128 * 4);

    (void)hipMemsetAsync(flag, 0, 4, stream);
    (void)hipMemsetAsync(counts, 0, (size_t)N * 4, stream);
    (void)hipMemsetAsync(cursor, 0, (size_t)N * 4, stream);

    int egrid = (E + BLK - 1) / BLK;
    detect_kernel<<<4, BLK, 0, stream>>>((const unsigned int*)ei, flag);
    hist_kernel<<<egrid, BLK, 0, stream>>>(ei, flag, E, counts);
    scan_kernel<<<1, BLK, 0, stream>>>(counts, offsets, N);
    scatter_pos_kernel<<<egrid, BLK, 0, stream>>>(ei, flag, offsets, cursor, meta, E);
    permute_gather_kernel<<<(E * 4 + BLK - 1) / BLK, BLK, 0, stream>>>(
        meta, (const float4*)ea, srcp, (float4*)eap, E);

    int ngrid4 = (N + 3) / 4;
    int ggrid  = (N + 63) / 64;

    // layer 0: d=64
    aggregate_kernel<64><<<ngrid4, BLK, 0, stream>>>(x_in, eap, srcp, We[0], be[0], offsets, bufA, N);
    mlp_kernel<64, false><<<ggrid, BLK, 0, stream>>>(bufA, W1[0], b1[0], W2[0], b2[0], bufC,
                                                     nullptr, nullptr, nullptr, N);
    // layer 1: d=128
    aggregate_kernel<128><<<ngrid4, BLK, 0, stream>>>(bufC, eap, srcp, We[1], be[1], offsets, bufA, N);
    mlp_kernel<128, false><<<ggrid, BLK, 0, stream>>>(bufA, W1[1], b1[1], W2[1], b2[1], bufC,
                                                      nullptr, nullptr, nullptr, N);
    // layer 2: d=128, head fused (sigmoid(res @ Wlin + blin) -> out)
    aggregate_kernel<128><<<ngrid4, BLK, 0, stream>>>(bufC, eap, srcp, We[2], be[2], offsets, bufA, N);
    mlp_kernel<128, true><<<ggrid, BLK, 0, stream>>>(bufA, W1[2], b1[2], W2[2], b2[2], nullptr,
                                                     Wlin, blin, out, N);
}